// Round 2
// baseline (529.087 us; speedup 1.0000x reference)
//
#include <hip/hip_runtime.h>

// Problem constants (fixed by the reference setup_inputs)
#define T_ 4096
#define D_ 4096
#define O_ 4096
#define L_ 32
#define R_ 8

constexpr int BM = 256, BN = 256, BK = 64;
constexpr int NT = D_ / BK;   // 64 K-tiles

typedef __bf16 bf16x8 __attribute__((ext_vector_type(8)));
typedef float f32x4 __attribute__((ext_vector_type(4)));

// fp32 -> bf16 round-to-nearest-even
__device__ __forceinline__ unsigned short f2bf(float f) {
    unsigned int u = __float_as_uint(f);
    u = (u + 0x7fffu + ((u >> 16) & 1u)) >> 16;
    return (unsigned short)u;
}

// async global->LDS, 16B per lane. LDS dest = wave-uniform base + lane*16.
__device__ __forceinline__ void load_lds16(const void* g, void* l) {
    __builtin_amdgcn_global_load_lds((__attribute__((address_space(1))) void*)g,
                                     (__attribute__((address_space(3))) void*)l,
                                     16, 0, 0);
}

// compiler-only memory fence (no instruction) + raw barrier (no vmcnt drain)
#define MEMF() asm volatile("" ::: "memory")
#define BARRIER() do { MEMF(); __builtin_amdgcn_s_barrier(); MEMF(); } while (0)

// ---------------------------------------------------------------------------
// Kernel 1 (fused prep): W fp32->bf16 convert (blocks 0..16383) and
// x convert + LoRA shrink (blocks 16384..20479, one block per token).
// ---------------------------------------------------------------------------
__global__ __launch_bounds__(256) void prep(const float* __restrict__ w,
                                            unsigned short* __restrict__ wbuf,
                                            const float* __restrict__ x,
                                            const float* __restrict__ lora_a,
                                            const int* __restrict__ tli,
                                            unsigned short* __restrict__ xbuf,
                                            float* __restrict__ shrink) {
    if (blockIdx.x < 16384) {
        const int i = (blockIdx.x * 256 + threadIdx.x) * 4;
        float4 v = *(const float4*)&w[i];
        ushort4 o;
        o.x = f2bf(v.x); o.y = f2bf(v.y); o.z = f2bf(v.z); o.w = f2bf(v.w);
        *(ushort4*)&wbuf[i] = o;
        return;
    }
    const int t = blockIdx.x - 16384;
    const int tid = threadIdx.x;
    const int lane = tid & 63;
    const int wave = tid >> 6;
    const int idx = tli[t];
    const float* xr = x + (size_t)t * D_;
    unsigned short* xo = xbuf + (size_t)t * D_;

    float acc[R_];
#pragma unroll
    for (int r = 0; r < R_; ++r) acc[r] = 0.0f;

    if (idx >= 0) {
        const float* ab = lora_a + (size_t)idx * R_ * D_;
#pragma unroll
        for (int j = 0; j < 4; ++j) {
            const int d = (j * 256 + tid) * 4;
            float4 v = *(const float4*)&xr[d];
            ushort4 o;
            o.x = f2bf(v.x); o.y = f2bf(v.y); o.z = f2bf(v.z); o.w = f2bf(v.w);
            *(ushort4*)&xo[d] = o;
#pragma unroll
            for (int r = 0; r < R_; ++r) {
                float4 a = *(const float4*)&ab[r * D_ + d];
                acc[r] += v.x * a.x + v.y * a.y + v.z * a.z + v.w * a.w;
            }
        }
    } else {
#pragma unroll
        for (int j = 0; j < 4; ++j) {
            const int d = (j * 256 + tid) * 4;
            float4 v = *(const float4*)&xr[d];
            ushort4 o;
            o.x = f2bf(v.x); o.y = f2bf(v.y); o.z = f2bf(v.z); o.w = f2bf(v.w);
            *(ushort4*)&xo[d] = o;
        }
    }

    __shared__ float red[4][R_];
#pragma unroll
    for (int r = 0; r < R_; ++r) {
        float v = acc[r];
#pragma unroll
        for (int off = 32; off > 0; off >>= 1) v += __shfl_xor(v, off, 64);
        if (lane == 0) red[wave][r] = v;
    }
    __syncthreads();
    if (tid < R_) {
        float s = red[0][tid] + red[1][tid] + red[2][tid] + red[3][tid];
        shrink[t * R_ + tid] = (idx >= 0) ? s : 0.0f;
    }
}

// ---------------------------------------------------------------------------
// Kernel 2: 256x256 bf16 MFMA GEMM, software-pipelined fragment reads.
// 8 waves (2Mx4N), wave owns 128x64 of C (acc[8][4] f32x4).
// Phase order per K-tile: P0(afLO,b01) P1(afLO,b23) P2(afHI,b01) P3(afHI,b23).
// ds_reads for phase p+1 are issued BEFORE phase p's MFMA (reg-level prefetch);
// cross-tile prefetch (afLO,b01 of t+1) issued in P2/P3 after the boundary
// vmcnt(6)+barrier. 3 barriers/tile; counted lgkmcnt(4)/(8); lgkmcnt(0) only
// at P2; vmcnt never drained to 0 in steady state.
// ---------------------------------------------------------------------------
__global__ __launch_bounds__(512, 2) void gemm_lora(const short* __restrict__ xb,
                                                    const short* __restrict__ wb,
                                                    const float* __restrict__ base_bias,
                                                    const float* __restrict__ lora_b,
                                                    const float* __restrict__ bias_st,
                                                    const int* __restrict__ tli,
                                                    const float* __restrict__ shrink,
                                                    float* __restrict__ out) {
    extern __shared__ short smem[];
    short* As0 = smem;                 // 256*64 shorts = 32 KB
    short* Bs0 = smem + 16384;
    short* As1 = smem + 32768;
    short* Bs1 = smem + 49152;

    const int tid = threadIdx.x;
    const int lane = tid & 63;
    const int wid = tid >> 6;          // 0..7
    const int wm = wid >> 2;           // 0..1
    const int wn = wid & 3;            // 0..3
    const int l15 = lane & 15;
    const int quad = lane >> 4;
    const int swz = l15 & 7;

    // bijective XCD swizzle over 256 blocks (16x16 tile grid, nwg%8==0)
    const int nid = (blockIdx.x & 7) * 32 + (blockIdx.x >> 3);
    const int t0 = (nid >> 4) * BM;
    const int o0 = (nid & 15) * BN;

    // staging source per-lane: row-within-8 = lane>>3, pre-swizzled chunk
    const int lr = lane >> 3;
    const int lc = (lane & 7) ^ lr;
    const short* ag = xb + (size_t)(t0 + wid * 8 + lr) * D_ + lc * 8;
    const short* bg = wb + (size_t)(o0 + wid * 8 + lr) * D_ + lc * 8;

    // region i covers tile rows [i*64, i*64+64); wave writes its 8 rows
    auto stA = [&](short* A_, int i, int kt) {
        load_lds16(ag + (size_t)i * 64 * D_ + kt * 64, A_ + (i * 64 + wid * 8) * 64);
    };
    auto stB = [&](short* B_, int i, int kt) {
        load_lds16(bg + (size_t)i * 64 * D_ + kt * 64, B_ + (i * 64 + wid * 8) * 64);
    };

    f32x4 acc[8][4];
#pragma unroll
    for (int mi = 0; mi < 8; ++mi)
#pragma unroll
        for (int ni = 0; ni < 4; ++ni) acc[mi][ni] = f32x4{0.f, 0.f, 0.f, 0.f};

    bf16x8 af[8][2];    // [0-3]=afLO, [4-7]=afHI
    bf16x8 bfr[4][2];   // [0-1]=b01,  [2-3]=b23

    const int arow0 = wm * 128 + l15;
    const int brow0 = wn * 64 + l15;

    auto rdA = [&](const short* A_, int mi, int kk) {
        return *(const bf16x8*)&A_[(arow0 + mi * 16) * 64 + (((kk << 2) + quad) ^ swz) * 8];
    };
    auto rdB = [&](const short* B_, int ni, int kk) {
        return *(const bf16x8*)&B_[(brow0 + ni * 16) * 64 + (((kk << 2) + quad) ^ swz) * 8];
    };

    // ---- prologue: stage tile0 -> buf0, tile1 -> buf1 ----
#pragma unroll
    for (int i = 0; i < 4; ++i) { stA(As0, i, 0); stB(Bs0, i, 0); }
    MEMF();
#pragma unroll
    for (int i = 0; i < 4; ++i) { stA(As1, i, 1); stB(Bs1, i, 1); }
    asm volatile("s_waitcnt vmcnt(8)" ::: "memory");   // tile0 landed
    BARRIER();
    // preload tile0: afLO + b01 (12 reads -> steady-state invariant)
#pragma unroll
    for (int mi = 0; mi < 4; ++mi)
#pragma unroll
        for (int kk = 0; kk < 2; ++kk) af[mi][kk] = rdA(As0, mi, kk);
    MEMF();
#pragma unroll
    for (int ni = 0; ni < 2; ++ni)
#pragma unroll
        for (int kk = 0; kk < 2; ++kk) bfr[ni][kk] = rdB(Bs0, ni, kk);
    MEMF();

    auto do_tile = [&](int t, short* A_, short* B_, short* An_, short* Bn_) {
        const bool st = (t + 2 < NT);
        const bool tail = (t >= NT - 2);
        const int k2 = t + 2;

        // -------- P0: MFMA afLO x b01; issue b23 reads first --------
#pragma unroll
        for (int ni = 2; ni < 4; ++ni)
#pragma unroll
            for (int kk = 0; kk < 2; ++kk) bfr[ni][kk] = rdB(B_, ni, kk);
        // outstanding: afLO(8)+b01(4)+b23(4)=16 -> oldest 12 done
        asm volatile("s_waitcnt lgkmcnt(4)" ::: "memory");
        BARRIER();   // all waves: afLO reads done -> A regions 0,2 free
        if (st) { stA(A_, 0, k2); stA(A_, 2, k2); }
        MEMF();
        __builtin_amdgcn_s_setprio(1);
#pragma unroll
        for (int kk = 0; kk < 2; ++kk)
#pragma unroll
            for (int mi = 0; mi < 4; ++mi)
#pragma unroll
                for (int ni = 0; ni < 2; ++ni)
                    acc[mi][ni] = __builtin_amdgcn_mfma_f32_16x16x32_bf16(
                        af[mi][kk], bfr[ni][kk], acc[mi][ni], 0, 0, 0);
        __builtin_amdgcn_s_setprio(0);
        MEMF();

        // -------- P1: MFMA afLO x b23; issue afHI reads first --------
#pragma unroll
        for (int mi = 4; mi < 8; ++mi)
#pragma unroll
            for (int kk = 0; kk < 2; ++kk) af[mi][kk] = rdA(A_, mi, kk);
        // outstanding: b23(4)+afHI(8)=12 -> oldest 4 (b23) done
        asm volatile("s_waitcnt lgkmcnt(8)" ::: "memory");
        BARRIER();   // all waves: b01+b23 reads done -> all B regions free
        if (st) { stB(B_, 0, k2); stB(B_, 1, k2); stB(B_, 2, k2); stB(B_, 3, k2); }
        MEMF();
        __builtin_amdgcn_s_setprio(1);
#pragma unroll
        for (int kk = 0; kk < 2; ++kk)
#pragma unroll
            for (int mi = 0; mi < 4; ++mi)
#pragma unroll
                for (int ni = 2; ni < 4; ++ni)
                    acc[mi][ni] = __builtin_amdgcn_mfma_f32_16x16x32_bf16(
                        af[mi][kk], bfr[ni][kk], acc[mi][ni], 0, 0, 0);
        __builtin_amdgcn_s_setprio(0);
        MEMF();

        // -------- P2: tile boundary; MFMA afHI x b01; prefetch afLO(t+1) ----
        if (!tail) { asm volatile("s_waitcnt vmcnt(6)" ::: "memory"); }
        else       { asm volatile("s_waitcnt vmcnt(0)" ::: "memory"); }
        asm volatile("s_waitcnt lgkmcnt(0)" ::: "memory");  // afHI done
        BARRIER();   // all waves: t+1 data landed; A regions 1,3 free
        if (st) { stA(A_, 1, k2); stA(A_, 3, k2); }
#pragma unroll
        for (int mi = 0; mi < 4; ++mi)
#pragma unroll
            for (int kk = 0; kk < 2; ++kk) af[mi][kk] = rdA(An_, mi, kk);
        MEMF();
        __builtin_amdgcn_s_setprio(1);
#pragma unroll
        for (int kk = 0; kk < 2; ++kk)
#pragma unroll
            for (int mi = 0; mi < 4; ++mi)
#pragma unroll
                for (int ni = 0; ni < 2; ++ni)
                    acc[mi + 4][ni] = __builtin_amdgcn_mfma_f32_16x16x32_bf16(
                        af[mi + 4][kk], bfr[ni][kk], acc[mi + 4][ni], 0, 0, 0);
        __builtin_amdgcn_s_setprio(0);
        MEMF();

        // -------- P3: MFMA afHI x b23; prefetch b01(t+1); no barrier --------
#pragma unroll
        for (int ni = 0; ni < 2; ++ni)
#pragma unroll
            for (int kk = 0; kk < 2; ++kk) bfr[ni][kk] = rdB(Bn_, ni, kk);
        MEMF();
        __builtin_amdgcn_s_setprio(1);
#pragma unroll
        for (int kk = 0; kk < 2; ++kk)
#pragma unroll
            for (int mi = 0; mi < 4; ++mi)
#pragma unroll
                for (int ni = 2; ni < 4; ++ni)
                    acc[mi + 4][ni] = __builtin_amdgcn_mfma_f32_16x16x32_bf16(
                        af[mi + 4][kk], bfr[ni][kk], acc[mi + 4][ni], 0, 0, 0);
        __builtin_amdgcn_s_setprio(0);
        MEMF();
    };

    for (int tt = 0; tt < NT; tt += 2) {
        do_tile(tt, As0, Bs0, As1, Bs1);
        do_tile(tt + 1, As1, Bs1, As0, Bs0);
    }

    // Epilogue: C/D layout col = lane&15, row = quad*4 + reg (verified mapping)
    const int col_base = o0 + wn * 64 + l15;
#pragma unroll
    for (int mi = 0; mi < 8; ++mi) {
#pragma unroll
        for (int reg = 0; reg < 4; ++reg) {
            const int row = t0 + wm * 128 + mi * 16 + quad * 4 + reg;
            const int idx = tli[row];
            const bool valid = (idx >= 0);
            float4 s0 = {0.f, 0.f, 0.f, 0.f}, s1 = {0.f, 0.f, 0.f, 0.f};
            if (valid) {
                s0 = *(const float4*)&shrink[row * R_];
                s1 = *(const float4*)&shrink[row * R_ + 4];
            }
#pragma unroll
            for (int ni = 0; ni < 4; ++ni) {
                const int col = col_base + ni * 16;
                float r = acc[mi][ni][reg] + base_bias[col];
                if (valid) {
                    const float* bp = &lora_b[((size_t)idx * O_ + col) * R_];
                    float4 b0 = *(const float4*)&bp[0];
                    float4 b1 = *(const float4*)&bp[4];
                    r += bias_st[(size_t)idx * O_ + col];
                    r += s0.x * b0.x + s0.y * b0.y + s0.z * b0.z + s0.w * b0.w +
                         s1.x * b1.x + s1.y * b1.y + s1.z * b1.z + s1.w * b1.w;
                }
                out[(size_t)row * O_ + col] = r;
            }
        }
    }
}

// ---------------------------------------------------------------------------
extern "C" void kernel_launch(void* const* d_in, const int* in_sizes, int n_in,
                              void* d_out, int out_size, void* d_ws, size_t ws_size,
                              hipStream_t stream) {
    const float* x    = (const float*)d_in[0];   // [T,D]
    const float* w    = (const float*)d_in[1];   // [O,D]
    const float* bb   = (const float*)d_in[2];   // [O]
    const float* la   = (const float*)d_in[3];   // [L,1,R,D]
    const float* lb   = (const float*)d_in[4];   // [L,1,O,R]
    const float* bs   = (const float*)d_in[5];   // [L,1,O]
    const int*   tli  = (const int*)d_in[6];     // [T]
    float* out = (float*)d_out;

    static bool inited = false;
    if (!inited) {
        (void)hipFuncSetAttribute((const void*)gemm_lora,
                                  hipFuncAttributeMaxDynamicSharedMemorySize, 131072);
        inited = true;
    }

    // workspace layout: xb (T*D bf16) | wb (O*D bf16) | shrink (T*R fp32)
    unsigned short* xb = (unsigned short*)d_ws;
    unsigned short* wb = xb + (size_t)T_ * D_;
    float* shrink = (float*)(wb + (size_t)O_ * D_);

    prep<<<16384 + T_, 256, 0, stream>>>(w, wb, x, la, tli, xb, shrink);
    gemm_lora<<<(T_ / BM) * (O_ / BN), 512, 131072, stream>>>(
        (const short*)xb, (const short*)wb, bb, lb, bs, tli, shrink, out);
}

// Round 3
// 337.844 us; speedup vs baseline: 1.5661x; 1.5661x over previous
//
#include <hip/hip_runtime.h>

// Problem constants (fixed by the reference setup_inputs)
#define T_ 4096
#define D_ 4096
#define O_ 4096
#define L_ 32
#define R_ 8

constexpr int BM = 256, BN = 256, BK = 64;
constexpr int KEXT = L_ * R_;            // 256 extension columns (4 K-tiles)
constexpr int NT = D_ / BK + KEXT / BK;  // 64 + 4 = 68 K-tiles (even)

typedef __bf16 bf16x8 __attribute__((ext_vector_type(8)));
typedef float f32x4 __attribute__((ext_vector_type(4)));

// fp32 -> bf16 round-to-nearest-even
__device__ __forceinline__ unsigned short f2bf(float f) {
    unsigned int u = __float_as_uint(f);
    u = (u + 0x7fffu + ((u >> 16) & 1u)) >> 16;
    return (unsigned short)u;
}

// async global->LDS, 16B per lane. LDS dest = wave-uniform base + lane*16.
__device__ __forceinline__ void load_lds16(const void* g, void* l) {
    __builtin_amdgcn_global_load_lds((__attribute__((address_space(1))) void*)g,
                                     (__attribute__((address_space(3))) void*)l,
                                     16, 0, 0);
}

// compiler-only memory fence (no instruction) + raw barrier (no vmcnt drain)
#define MEMF() asm volatile("" ::: "memory")
#define BARRIER() do { MEMF(); __builtin_amdgcn_s_barrier(); MEMF(); } while (0)

// ---------------------------------------------------------------------------
// Kernel 1 (fused prep), three sections by blockIdx.x:
//   [0, 16384)        : W fp32->bf16 convert into wb
//   [16384, 20480)    : per-token x convert + LoRA shrink + Aext row scatter
//   [20480, 21504)    : Bext build: Bext[o][l*8+r] = bf16(lora_b[l,0,o,r])
// ---------------------------------------------------------------------------
__global__ __launch_bounds__(256) void prep(const float* __restrict__ w,
                                            unsigned short* __restrict__ wbuf,
                                            const float* __restrict__ x,
                                            const float* __restrict__ lora_a,
                                            const float* __restrict__ lora_b,
                                            const int* __restrict__ tli,
                                            unsigned short* __restrict__ xbuf,
                                            unsigned short* __restrict__ aext,
                                            unsigned short* __restrict__ bext) {
    if (blockIdx.x < 16384) {
        const int i = (blockIdx.x * 256 + threadIdx.x) * 4;
        float4 v = *(const float4*)&w[i];
        ushort4 o;
        o.x = f2bf(v.x); o.y = f2bf(v.y); o.z = f2bf(v.z); o.w = f2bf(v.w);
        *(ushort4*)&wbuf[i] = o;
        return;
    }
    if (blockIdx.x >= 20480) {
        // Bext section: 4 output rows per block, one 64-lane wave per row.
        const int o = (blockIdx.x - 20480) * 4 + (threadIdx.x >> 6);
        const int lane = threadIdx.x & 63;
        const int l = lane >> 1;                 // lora id 0..31
        const int r0 = (lane & 1) * 4;           // r offset 0 or 4
        float4 v = *(const float4*)&lora_b[((size_t)l * O_ + o) * R_ + r0];
        ushort4 ov;
        ov.x = f2bf(v.x); ov.y = f2bf(v.y); ov.z = f2bf(v.z); ov.w = f2bf(v.w);
        *(ushort4*)&bext[(size_t)o * KEXT + lane * 4] = ov;
        return;
    }
    // token section
    const int t = blockIdx.x - 16384;
    const int tid = threadIdx.x;
    const int lane = tid & 63;
    const int wave = tid >> 6;
    const int idx = tli[t];
    const float* xr = x + (size_t)t * D_;
    unsigned short* xo = xbuf + (size_t)t * D_;

    float acc[R_];
#pragma unroll
    for (int r = 0; r < R_; ++r) acc[r] = 0.0f;

    if (idx >= 0) {
        const float* ab = lora_a + (size_t)idx * R_ * D_;
#pragma unroll
        for (int j = 0; j < 4; ++j) {
            const int d = (j * 256 + tid) * 4;
            float4 v = *(const float4*)&xr[d];
            ushort4 o;
            o.x = f2bf(v.x); o.y = f2bf(v.y); o.z = f2bf(v.z); o.w = f2bf(v.w);
            *(ushort4*)&xo[d] = o;
#pragma unroll
            for (int r = 0; r < R_; ++r) {
                float4 a = *(const float4*)&ab[r * D_ + d];
                acc[r] += v.x * a.x + v.y * a.y + v.z * a.z + v.w * a.w;
            }
        }
    } else {
#pragma unroll
        for (int j = 0; j < 4; ++j) {
            const int d = (j * 256 + tid) * 4;
            float4 v = *(const float4*)&xr[d];
            ushort4 o;
            o.x = f2bf(v.x); o.y = f2bf(v.y); o.z = f2bf(v.z); o.w = f2bf(v.w);
            *(ushort4*)&xo[d] = o;
        }
    }

    __shared__ float red[4][R_];
#pragma unroll
    for (int r = 0; r < R_; ++r) {
        float v = acc[r];
#pragma unroll
        for (int off = 32; off > 0; off >>= 1) v += __shfl_xor(v, off, 64);
        if (lane == 0) red[wave][r] = v;
    }
    __syncthreads();
    // Aext row: col l*8+r holds bf16(shrink[r]) iff l == idx, else 0.
    {
        const int col = tid;                 // 0..255 == KEXT
        const int r = col & 7;
        const float sv = red[0][r] + red[1][r] + red[2][r] + red[3][r];
        const unsigned short val = ((col >> 3) == idx) ? f2bf(sv) : (unsigned short)0;
        aext[(size_t)t * KEXT + col] = val;
    }
}

// ---------------------------------------------------------------------------
// Kernel 2: 256x256 bf16 MFMA GEMM over K = 4096 + 256 (LoRA expand folded in
// as 4 extra K-tiles read from aext/bext). Round-1-proven phase skeleton:
// per K-tile 4 phases of {ds_reads; barrier; setprio MFMA x16 setprio; barrier},
// staging for tile t+2 spread at phase starts, vmcnt(8) once per tile.
// Epilogue: out = acc + base_bias + (valid ? bias_st : 0). No lora_b gathers.
// ---------------------------------------------------------------------------
__global__ __launch_bounds__(512, 2) void gemm_lora(const short* __restrict__ xb,
                                                    const short* __restrict__ wb,
                                                    const short* __restrict__ aext,
                                                    const short* __restrict__ bext,
                                                    const float* __restrict__ base_bias,
                                                    const float* __restrict__ bias_st,
                                                    const int* __restrict__ tli,
                                                    float* __restrict__ out) {
    extern __shared__ short smem[];
    short* As0 = smem;                 // 256*64 shorts = 32 KB
    short* Bs0 = smem + 16384;
    short* As1 = smem + 32768;
    short* Bs1 = smem + 49152;

    const int tid = threadIdx.x;
    const int lane = tid & 63;
    const int wid = tid >> 6;          // 0..7
    const int wm = wid >> 2;           // 0..1
    const int wn = wid & 3;            // 0..3
    const int l15 = lane & 15;
    const int quad = lane >> 4;
    const int swz = l15 & 7;

    // bijective XCD swizzle over 256 blocks (16x16 tile grid, nwg%8==0)
    const int nid = (blockIdx.x & 7) * 32 + (blockIdx.x >> 3);
    const int t0 = (nid >> 4) * BM;
    const int o0 = (nid & 15) * BN;

    // staging source per-lane: row-within-8 = lane>>3, pre-swizzled chunk
    const int lr = lane >> 3;
    const int lc = (lane & 7) ^ lr;
    const short* agD = xb   + (size_t)(t0 + wid * 8 + lr) * D_   + lc * 8;
    const short* bgD = wb   + (size_t)(o0 + wid * 8 + lr) * D_   + lc * 8;
    const short* agE = aext + (size_t)(t0 + wid * 8 + lr) * KEXT + lc * 8;
    const short* bgE = bext + (size_t)(o0 + wid * 8 + lr) * KEXT + lc * 8;

    // region i covers tile rows [i*64, i*64+64); wave writes its 8 rows.
    // kt < 64 reads the main matrices; kt >= 64 reads the extension buffers.
    auto stA = [&](short* A_, int i, int kt) {
        const short* src = (kt < 64)
            ? agD + (size_t)i * 64 * D_   + (size_t)kt * 64
            : agE + (size_t)i * 64 * KEXT + (size_t)(kt - 64) * 64;
        load_lds16(src, A_ + (i * 64 + wid * 8) * 64);
    };
    auto stB = [&](short* B_, int i, int kt) {
        const short* src = (kt < 64)
            ? bgD + (size_t)i * 64 * D_   + (size_t)kt * 64
            : bgE + (size_t)i * 64 * KEXT + (size_t)(kt - 64) * 64;
        load_lds16(src, B_ + (i * 64 + wid * 8) * 64);
    };

    f32x4 acc[8][4];
#pragma unroll
    for (int mi = 0; mi < 8; ++mi)
#pragma unroll
        for (int ni = 0; ni < 4; ++ni) acc[mi][ni] = f32x4{0.f, 0.f, 0.f, 0.f};

    bf16x8 af[4][2];    // current qm-half A frags (reused for HI half)
    bf16x8 bfr[4][2];   // all B frags, live across the whole K-tile

    const int arow0 = wm * 128 + l15;
    const int brow0 = wn * 64 + l15;

    auto rdA = [&](const short* A_, int mi, int kk) {
        return *(const bf16x8*)&A_[(arow0 + mi * 16) * 64 + (((kk << 2) + quad) ^ swz) * 8];
    };
    auto rdB = [&](const short* B_, int ni, int kk) {
        return *(const bf16x8*)&B_[(brow0 + ni * 16) * 64 + (((kk << 2) + quad) ^ swz) * 8];
    };

    // prologue: tile 0 -> buf0, tile 1 -> buf1. Group order [A0,A2,B0..B3,A1,A3]
    stA(As0, 0, 0); stA(As0, 2, 0); stB(Bs0, 0, 0); stB(Bs0, 1, 0);
    stB(Bs0, 2, 0); stB(Bs0, 3, 0); stA(As0, 1, 0); stA(As0, 3, 0);
    stA(As1, 0, 1); stA(As1, 2, 1); stB(Bs1, 0, 1); stB(Bs1, 1, 1);
    stB(Bs1, 2, 1); stB(Bs1, 3, 1); stA(As1, 1, 1); stA(As1, 3, 1);
    asm volatile("s_waitcnt vmcnt(8)" ::: "memory");   // tile 0 landed, tile 1 in flight
    BARRIER();

    auto do_tile = [&](int t, short* A_, short* B_) {
        const bool st = (t + 2 < NT);
        const int k2 = t + 2;

        // ---- phase 0: read A[mi0-3]+B[ni0-1]; MFMA mi0-3 x ni0-1
#pragma unroll
        for (int mi = 0; mi < 4; ++mi)
#pragma unroll
            for (int kk = 0; kk < 2; ++kk) af[mi][kk] = rdA(A_, mi, kk);
#pragma unroll
        for (int ni = 0; ni < 2; ++ni)
#pragma unroll
            for (int kk = 0; kk < 2; ++kk) bfr[ni][kk] = rdB(B_, ni, kk);
        BARRIER();
        __builtin_amdgcn_s_setprio(1);
#pragma unroll
        for (int kk = 0; kk < 2; ++kk)
#pragma unroll
            for (int mi = 0; mi < 4; ++mi)
#pragma unroll
                for (int ni = 0; ni < 2; ++ni)
                    acc[mi][ni] = __builtin_amdgcn_mfma_f32_16x16x32_bf16(
                        af[mi][kk], bfr[ni][kk], acc[mi][ni], 0, 0, 0);
        __builtin_amdgcn_s_setprio(0);
        BARRIER();   // A regions 0,2 of this buf fully consumed

        // ---- phase 1: stage t+2 A0,A2; read B[ni2-3]; MFMA mi0-3 x ni2-3
        if (st) { stA(A_, 0, k2); stA(A_, 2, k2); }
#pragma unroll
        for (int ni = 2; ni < 4; ++ni)
#pragma unroll
            for (int kk = 0; kk < 2; ++kk) bfr[ni][kk] = rdB(B_, ni, kk);
        BARRIER();
        __builtin_amdgcn_s_setprio(1);
#pragma unroll
        for (int kk = 0; kk < 2; ++kk)
#pragma unroll
            for (int mi = 0; mi < 4; ++mi)
#pragma unroll
                for (int ni = 2; ni < 4; ++ni)
                    acc[mi][ni] = __builtin_amdgcn_mfma_f32_16x16x32_bf16(
                        af[mi][kk], bfr[ni][kk], acc[mi][ni], 0, 0, 0);
        __builtin_amdgcn_s_setprio(0);
        BARRIER();   // all B regions of this buf fully consumed

        // ---- phase 2: stage t+2 B0-B3; read A[mi4-7]; MFMA mi4-7 x ni0-1
        if (st) { stB(B_, 0, k2); stB(B_, 1, k2); stB(B_, 2, k2); stB(B_, 3, k2); }
#pragma unroll
        for (int mi = 0; mi < 4; ++mi)
#pragma unroll
            for (int kk = 0; kk < 2; ++kk) af[mi][kk] = rdA(A_, mi + 4, kk);
        BARRIER();
        __builtin_amdgcn_s_setprio(1);
#pragma unroll
        for (int kk = 0; kk < 2; ++kk)
#pragma unroll
            for (int mi = 0; mi < 4; ++mi)
#pragma unroll
                for (int ni = 0; ni < 2; ++ni)
                    acc[mi + 4][ni] = __builtin_amdgcn_mfma_f32_16x16x32_bf16(
                        af[mi][kk], bfr[ni][kk], acc[mi + 4][ni], 0, 0, 0);
        __builtin_amdgcn_s_setprio(0);
        BARRIER();   // A regions 1,3 of this buf fully consumed

        // ---- phase 3: stage t+2 A1,A3; MFMA mi4-7 x ni2-3; tile-end wait
        if (st) { stA(A_, 1, k2); stA(A_, 3, k2); }
        BARRIER();
        __builtin_amdgcn_s_setprio(1);
#pragma unroll
        for (int kk = 0; kk < 2; ++kk)
#pragma unroll
            for (int mi = 0; mi < 4; ++mi)
#pragma unroll
                for (int ni = 2; ni < 4; ++ni)
                    acc[mi + 4][ni] = __builtin_amdgcn_mfma_f32_16x16x32_bf16(
                        af[mi][kk], bfr[ni][kk], acc[mi + 4][ni], 0, 0, 0);
        __builtin_amdgcn_s_setprio(0);
        // youngest 8 outstanding = tile t+2's group -> tiles t+1 (and older) landed
        if (st) { asm volatile("s_waitcnt vmcnt(8)" ::: "memory"); }
        else    { asm volatile("s_waitcnt vmcnt(0)" ::: "memory"); }
        BARRIER();
    };

    for (int tt = 0; tt < NT; tt += 2) {
        do_tile(tt, As0, Bs0);
        do_tile(tt + 1, As1, Bs1);
    }

    // Epilogue: C/D layout col = lane&15, row = quad*4 + reg (verified mapping)
    const int col_base = o0 + wn * 64 + l15;
    float bb[4];
#pragma unroll
    for (int ni = 0; ni < 4; ++ni) bb[ni] = base_bias[col_base + ni * 16];
#pragma unroll
    for (int mi = 0; mi < 8; ++mi) {
#pragma unroll
        for (int reg = 0; reg < 4; ++reg) {
            const int row = t0 + wm * 128 + mi * 16 + quad * 4 + reg;
            const int idx = tli[row];
            const bool valid = (idx >= 0);
#pragma unroll
            for (int ni = 0; ni < 4; ++ni) {
                const int col = col_base + ni * 16;
                float r = acc[mi][ni][reg] + bb[ni];
                if (valid) r += bias_st[(size_t)idx * O_ + col];
                out[(size_t)row * O_ + col] = r;
            }
        }
    }
}

// ---------------------------------------------------------------------------
extern "C" void kernel_launch(void* const* d_in, const int* in_sizes, int n_in,
                              void* d_out, int out_size, void* d_ws, size_t ws_size,
                              hipStream_t stream) {
    const float* x    = (const float*)d_in[0];   // [T,D]
    const float* w    = (const float*)d_in[1];   // [O,D]
    const float* bb   = (const float*)d_in[2];   // [O]
    const float* la   = (const float*)d_in[3];   // [L,1,R,D]
    const float* lb   = (const float*)d_in[4];   // [L,1,O,R]
    const float* bs   = (const float*)d_in[5];   // [L,1,O]
    const int*   tli  = (const int*)d_in[6];     // [T]
    float* out = (float*)d_out;

    static bool inited = false;
    if (!inited) {
        (void)hipFuncSetAttribute((const void*)gemm_lora,
                                  hipFuncAttributeMaxDynamicSharedMemorySize, 131072);
        inited = true;
    }

    // workspace: xb (T*D bf16) | wb (O*D bf16) | aext (T*256 bf16) | bext (O*256 bf16)
    unsigned short* xb = (unsigned short*)d_ws;
    unsigned short* wb = xb + (size_t)T_ * D_;
    unsigned short* aext = wb + (size_t)O_ * D_;
    unsigned short* bext = aext + (size_t)T_ * KEXT;

    prep<<<16384 + T_ + O_ / 4, 256, 0, stream>>>(w, wb, x, la, lb, tli, xb, aext, bext);
    gemm_lora<<<(T_ / BM) * (O_ / BN), 512, 131072, stream>>>(
        (const short*)xb, (const short*)wb, (const short*)aext, (const short*)bext,
        bb, bs, tli, out);
}